// Round 3
// baseline (274.020 us; speedup 1.0000x reference)
//
#include <hip/hip_runtime.h>
#include <cmath>

#define B_N 65536
#define C_N 128
#define D_N 32
#define DH  33                  // homogeneous dim (z, 1)
#define PPAD 616                // packed row: each triangle row padded to x4 floats (612 used)
#define K_N 10
#define CTILE 8
#define EPS_F 1e-12f
#define SCALE_F (-0.72134752044448169f)   // -0.5 * log2(e)

// ---------------------------------------------------------------------------
// Fused prep (1 block per cluster): Sm, t3, cls, and pack P.
// P row layout: for d=0..32, row of m4(d)*4 floats at off(d), where
// m4(d) = (36-d)>>2 = ceil((33-d)/4). Entry j of row d (j < 33-d) is
// SCALE * Mhat[d][d+j]; pad entries are 0.
//   Mhat[d][e] (d<=e): d,e<32 : S[d][e]*(d==e?1:2)
//                      e==32,d<32 : -2*Sm[d]
//                      d==e==32   : t3
// ---------------------------------------------------------------------------
__global__ __launch_bounds__(64) void k_prep(const float* __restrict__ S,
                                             const float* __restrict__ mu,
                                             const int* __restrict__ onehot,
                                             float* __restrict__ P,
                                             int* __restrict__ cls) {
    int c = blockIdx.x;
    int tid = threadIdx.x;
    __shared__ float sSm[D_N];
    __shared__ float sT3;

    if (tid < D_N) {
        const float* Sr = S + (size_t)c * (D_N * D_N) + (size_t)tid * D_N;
        const float* mr = mu + (size_t)c * D_N;
        float a0 = 0.f, a1 = 0.f, a2 = 0.f, a3 = 0.f;
#pragma unroll
        for (int e = 0; e < D_N; e += 4) {
            a0 = fmaf(Sr[e + 0], mr[e + 0], a0);
            a1 = fmaf(Sr[e + 1], mr[e + 1], a1);
            a2 = fmaf(Sr[e + 2], mr[e + 2], a2);
            a3 = fmaf(Sr[e + 3], mr[e + 3], a3);
        }
        sSm[tid] = (a0 + a1) + (a2 + a3);
    }
    __syncthreads();
    if (tid == 0) {
        const float* mr = mu + (size_t)c * D_N;
        float a = 0.f;
#pragma unroll
        for (int d = 0; d < D_N; ++d) a = fmaf(mr[d], sSm[d], a);
        sT3 = a;
        int cl = 0;
#pragma unroll
        for (int k = 0; k < K_N; ++k)
            if (onehot[c * K_N + k] != 0) cl = k;
        cls[c] = cl;
    }
    __syncthreads();
    if (tid < DH) {
        int d = tid;
        int off = 0;
        for (int dd = 0; dd < d; ++dd) off += ((36 - dd) >> 2) << 2;
        int n = DH - d;
        int m = ((36 - d) >> 2) << 2;
        float* Pr = P + (size_t)c * PPAD + off;
        for (int j = 0; j < m; ++j) {
            float v;
            if (j >= n) {
                v = 0.f;
            } else {
                int e = d + j;
                if (e < D_N)      v = S[(size_t)c * (D_N * D_N) + d * D_N + e] * (d == e ? 1.f : 2.f);
                else if (d < D_N) v = -2.f * sSm[d];
                else              v = sT3;
            }
            Pr[j] = SCALE_F * v;
        }
    }
}

// ---------------------------------------------------------------------------
// Main: Gamma[c][b] = exp2( sum_{d<=e} P[c] y_d y_e ), P tile staged in LDS.
// grid (B/256, C/CTILE). LDS reads are wave-uniform float4 broadcasts.
// ---------------------------------------------------------------------------
__global__ __launch_bounds__(256) void k_main(const float* __restrict__ data,
                                              const float* __restrict__ P,
                                              float* __restrict__ gws) {
    __shared__ __align__(16) float sP[CTILE * PPAD];   // 19712 B
    int tid = threadIdx.x;
    int b = blockIdx.x * 256 + tid;
    int c0 = blockIdx.y * CTILE;

    // Stage this block's 8-cluster P tile (coalesced float4).
    {
        const float4* gp = (const float4*)(P + (size_t)c0 * PPAD);
        float4* sp = (float4*)sP;
        for (int i = tid; i < CTILE * PPAD / 4; i += 256) sp[i] = gp[i];
    }

    float y[36];
    {
        const float4* dz = (const float4*)(data + (size_t)b * D_N);
#pragma unroll
        for (int i = 0; i < D_N / 4; ++i) {
            float4 v = dz[i];
            y[4 * i + 0] = v.x;
            y[4 * i + 1] = v.y;
            y[4 * i + 2] = v.z;
            y[4 * i + 3] = v.w;
        }
        y[32] = 1.0f;
        y[33] = 0.f; y[34] = 0.f; y[35] = 0.f;
    }
    __syncthreads();

    for (int cc = 0; cc < CTILE; ++cc) {
        const float* Pc = sP + cc * PPAD;
        float a0 = 0.f, a1 = 0.f;
        int off = 0;
#pragma unroll
        for (int d = 0; d < DH; ++d) {
            const int m4 = (36 - d) >> 2;          // float4s in this row
            float u0 = 0.f, u1 = 0.f;
#pragma unroll
            for (int j = 0; j < m4; ++j) {
                float4 p = *(const float4*)(Pc + off + 4 * j);
                u0 = fmaf(p.x, y[d + 4 * j + 0], u0);
                u1 = fmaf(p.y, y[d + 4 * j + 1], u1);
                u0 = fmaf(p.z, y[d + 4 * j + 2], u0);
                u1 = fmaf(p.w, y[d + 4 * j + 3], u1);
            }
            off += m4 * 4;
            float ud = u0 + u1;
            if (d & 1) a1 = fmaf(y[d], ud, a1);
            else       a0 = fmaf(y[d], ud, a0);
        }
        float acc = a0 + a1;                        // = -0.5*log2e * d2
        float g;
        asm("v_exp_f32 %0, %1" : "=v"(g) : "v"(acc));   // 2^acc
        gws[(size_t)(c0 + cc) * B_N + b] = g;       // coalesced store
    }
}

// ---------------------------------------------------------------------------
// Finalize: 4 waves per 64 rows; each wave scans a 32-cluster chunk, LDS
// combine. d_out (float32): [B*K scores][B preds][B clusters]
// ---------------------------------------------------------------------------
__global__ __launch_bounds__(256) void k_final(const float* __restrict__ gws,
                                               const int* __restrict__ cls,
                                               float* __restrict__ out) {
    __shared__ float comb[4][64][16];
    int tid   = threadIdx.x;
    int lane  = tid & 63;
    int chunk = tid >> 6;
    int b0 = blockIdx.x * 64;
    int b  = b0 + lane;

    float s = 0.f, gmax = -1.f;
    int amax = 0;
    float a0 = 0, a1 = 0, a2 = 0, a3 = 0, a4 = 0, a5 = 0, a6 = 0, a7 = 0, a8 = 0, a9 = 0;
    int cbase = chunk * 32;
    for (int i = 0; i < 32; ++i) {
        int c = cbase + i;
        float g = gws[(size_t)c * B_N + b];
        s += g;
        if (g > gmax) { gmax = g; amax = c; }
        int cl = cls[c];
        if      (cl == 0) a0 += g;
        else if (cl == 1) a1 += g;
        else if (cl == 2) a2 += g;
        else if (cl == 3) a3 += g;
        else if (cl == 4) a4 += g;
        else if (cl == 5) a5 += g;
        else if (cl == 6) a6 += g;
        else if (cl == 7) a7 += g;
        else if (cl == 8) a8 += g;
        else              a9 += g;
    }
    float* cw = comb[chunk][lane];
    cw[0] = s; cw[1] = gmax; cw[2] = (float)amax;
    cw[3] = a0; cw[4] = a1; cw[5] = a2; cw[6] = a3; cw[7] = a4;
    cw[8] = a5; cw[9] = a6; cw[10] = a7; cw[11] = a8; cw[12] = a9;
    __syncthreads();

    if (tid < 64) {
        int row = tid;
        float sum = 0.f, gm = -1.f;
        int am = 0;
        float acc[K_N];
#pragma unroll
        for (int k = 0; k < K_N; ++k) acc[k] = 0.f;
#pragma unroll
        for (int ch = 0; ch < 4; ++ch) {
            const float* cr = comb[ch][row];
            sum += cr[0];
            if (cr[1] > gm) { gm = cr[1]; am = (int)cr[2]; }
#pragma unroll
            for (int k = 0; k < K_N; ++k) acc[k] += cr[3 + k];
        }
        float inv = 1.0f / (sum + EPS_F);
        float best = -1.f;
        int bk = 0;
        float ls[K_N];
#pragma unroll
        for (int k = 0; k < K_N; ++k) {
            ls[k] = acc[k] * inv;
            if (ls[k] > best) { best = ls[k]; bk = k; }
        }
        int bb = b0 + row;
#pragma unroll
        for (int k = 0; k < K_N; ++k) out[(size_t)bb * K_N + k] = ls[k];
        out[(size_t)B_N * K_N + bb] = (float)bk;
        out[(size_t)B_N * K_N + B_N + bb] = (float)am;
    }
}

// ---------------------------------------------------------------------------
extern "C" void kernel_launch(void* const* d_in, const int* in_sizes, int n_in,
                              void* d_out, int out_size, void* d_ws, size_t ws_size,
                              hipStream_t stream) {
    const float* data   = (const float*)d_in[0];   // [B, D]
    const float* mu     = (const float*)d_in[1];   // [C, D]
    const float* S      = (const float*)d_in[2];   // [C, D, D]
    const int*   onehot = (const int*)d_in[3];     // [C, K]
    float* out = (float*)d_out;

    // ws: Gamma [C][B] | P [C*PPAD] | cls [C]
    float* gws = (float*)d_ws;
    float* P   = gws + (size_t)C_N * B_N;
    int*   cls = (int*)(P + (size_t)C_N * PPAD);

    hipLaunchKernelGGL(k_prep, dim3(C_N), dim3(64), 0, stream,
                       S, mu, onehot, P, cls);
    hipLaunchKernelGGL(k_main, dim3(B_N / 256, C_N / CTILE), dim3(256), 0, stream,
                       data, P, gws);
    hipLaunchKernelGGL(k_final, dim3(B_N / 64), dim3(256), 0, stream,
                       gws, cls, out);
}